// Round 11
// baseline (1786.934 us; speedup 1.0000x reference)
//
#include <hip/hip_runtime.h>
#include <hip/hip_bf16.h>
#include <stdint.h>

#define N_RES 4096
#define BATCH 8
#define T_STEPS 256
#define VOCAB 32000
#define R_OUT 512
#define NNZ 131072
#define NNZ_CAP 163840
#define TEAMS 8             // one per batch
#define SLICES 16           // WGs per team
#define ROWS_PS 256         // rows per WG
#define NWG (TEAMS*SLICES)  // 128
#define CSR_CAP 10240       // entries per slice in LDS (mean ~9088, +11 sigma)

typedef _Float16 v8h __attribute__((ext_vector_type(8)));
typedef float v4f __attribute__((ext_vector_type(4)));

static __device__ __forceinline__ unsigned short f2h(float f) {
    _Float16 h = (_Float16)f;
    unsigned short u;
    __builtin_memcpy(&u, &h, 2);
    return u;
}
static __device__ __forceinline__ float h2f(unsigned short u) {
    _Float16 h;
    __builtin_memcpy(&h, &u, 2);
    return (float)h;
}

// ---------------- fused init: zero csr, cnt, hxL, hxG (one node) ----------------

#define HX_WORDS (2 * TEAMS * 4096)             // 65536 u32 per buffer
#define INIT_WORDS (NNZ_CAP + 4096 + 2 * HX_WORDS)

__global__ __launch_bounds__(256) void k_init(unsigned* __restrict__ csr,
                                              int* __restrict__ cnt,
                                              unsigned* __restrict__ hxL,
                                              unsigned* __restrict__ hxG) {
    int i = blockIdx.x * 256 + threadIdx.x;
    if (i < NNZ_CAP) csr[i] = 0u;
    else if (i < NNZ_CAP + 4096) cnt[i - NNZ_CAP] = 0;
    else if (i < NNZ_CAP + 4096 + HX_WORDS) hxL[i - NNZ_CAP - 4096] = 0u;
    else if (i < INIT_WORDS) hxG[i - NNZ_CAP - 4096 - HX_WORDS] = 0u;
}

// ---------------- CSR build ----------------

__global__ __launch_bounds__(256) void k_hist(const int* __restrict__ rows,
                                              int* __restrict__ cnt) {
    int i = blockIdx.x * 256 + threadIdx.x;
    if (i < NNZ) atomicAdd(&cnt[rows[i]], 1);
}

// padded scan: each row's span rounded up to multiple of 8
__global__ __launch_bounds__(1024) void k_scan(const int* __restrict__ cnt,
                                               int* __restrict__ row_ptr,
                                               int* __restrict__ cursor) {
    __shared__ int sm[1024];
    int t = threadIdx.x;
    int base = t * 4;
    int c0 = (cnt[base] + 7) & ~7;
    int c1 = (cnt[base + 1] + 7) & ~7;
    int c2 = (cnt[base + 2] + 7) & ~7;
    int c3 = (cnt[base + 3] + 7) & ~7;
    int s = c0 + c1 + c2 + c3;
    sm[t] = s;
    __syncthreads();
    for (int off = 1; off < 1024; off <<= 1) {
        int v = (t >= off) ? sm[t - off] : 0;
        __syncthreads();
        sm[t] += v;
        __syncthreads();
    }
    int run = sm[t] - s;
    row_ptr[base] = run;     cursor[base] = run;     run += c0;
    row_ptr[base + 1] = run; cursor[base + 1] = run; run += c1;
    row_ptr[base + 2] = run; cursor[base + 2] = run; run += c2;
    row_ptr[base + 3] = run; cursor[base + 3] = run; run += c3;
    if (t == 1023) row_ptr[4096] = run;
}

// packed CSR entry: plane BYTE offset (col*4) in hi16, f16 value in lo16.
__global__ __launch_bounds__(256) void k_fill(const int* __restrict__ rows,
                                              const int* __restrict__ cols,
                                              const float* __restrict__ vals,
                                              int* __restrict__ cursor,
                                              unsigned* __restrict__ csr) {
    int i = blockIdx.x * 256 + threadIdx.x;
    if (i < NNZ) {
        int r = rows[i];
        unsigned off = (unsigned)(cols[i] << 2);
        int p = atomicAdd(&cursor[r], 1);
        csr[p] = (off << 16) | (unsigned)f2h(vals[i]);
    }
}

// ---------------- fused f32 -> f16 convert: B_w then A_w (one node) ----------------

#define NB8 (R_OUT * N_RES / 8)     // 262144 B_w octets
#define NA8 (VOCAB * R_OUT / 8)     // 2048000 A_w octets

__global__ __launch_bounds__(256) void k_cvt2(const float* __restrict__ Bw,
                                              unsigned short* __restrict__ Bwh,
                                              const float* __restrict__ Aw,
                                              unsigned short* __restrict__ Awh) {
    int i = blockIdx.x * 256 + threadIdx.x;
    const float* src;
    unsigned short* dst;
    int j;
    if (i < NB8) { src = Bw; dst = Bwh; j = i * 8; }
    else if (i < NB8 + NA8) { src = Aw; dst = Awh; j = (i - NB8) * 8; }
    else return;
    float4 a0 = *reinterpret_cast<const float4*>(src + j);
    float4 a1 = *reinterpret_cast<const float4*>(src + j + 4);
    unsigned short o[8] = { f2h(a0.x), f2h(a0.y), f2h(a0.z), f2h(a0.w),
                            f2h(a1.x), f2h(a1.y), f2h(a1.z), f2h(a1.w) };
    *reinterpret_cast<uint4*>(dst + j) = *reinterpret_cast<const uint4*>(o);
}

// ---------------- persistent recurrence: L2-local fast exchange + safe fallback ----
// 128 WGs x 256 threads. team = wg>>4 (16 CONSECUTIVE WGs: chunked-dispatch
// locality hypothesis), slice = wg&15. Tagged word u32 = (epoch<<16)|f16(h),
// parity double-buffered; DUAL publish:
//   hxL: plain (workgroup-scope) store -> write-through L1 into this XCD's L2.
//   hxG: relaxed agent store -> MALL-visible under any WG placement.
// Pull: sc0 loads (SE scope: bypass L1, served by local L2) of hxL with a
// 256-try budget. If producers share the XCD, tags validate in ~L2 latency.
// If not, the consumer's L2 caches a permanently-stale line -> budget
// exhausts -> STICKY per-WG fallback to agent-scope pull of hxG (r7-proven
// protocol) for all remaining steps. No flags, no vmcnt: the tag IS the
// readiness signal on both paths; correctness never depends on WG->XCD
// mapping (G16-safe), only speed does.
// Overwrite safety (parity induction, r7): producer publishes e only after
// fully pulling e-1, which required all producers to publish e-1, hence all
// WGs consumed e-2 (same-parity words) before any e word lands.
// hxL/hxG zeroed every launch by k_init -> replay-safe.

__global__ __launch_bounds__(256) void k_steps(const int* __restrict__ rowptr,
                                               const unsigned* __restrict__ csr,
                                               const float* __restrict__ W_in,
                                               const int* __restrict__ x,
                                               const float* __restrict__ a,
                                               unsigned short* __restrict__ Hb,
                                               unsigned* __restrict__ hxL,
                                               unsigned* __restrict__ hxG) {
    __shared__ float plane[4096];                       // 16 KB, identity layout
    __shared__ __align__(16) unsigned lcsr[CSR_CAP];    // 40 KB
    __shared__ int ltok[T_STEPS];                       // 1 KB
    __shared__ int s_fb;                                // sticky fallback flag

    int wg = blockIdx.x;
    int tid = threadIdx.x;
    int team = wg >> 4;
    int slice = wg & 15;
    int r_own = slice * ROWS_PS + tid;

    if (tid == 0) s_fb = 0;
    ltok[tid] = x[team * T_STEPS + tid];

    int j0 = rowptr[slice * ROWS_PS];
    int j1 = rowptr[slice * ROWS_PS + ROWS_PS];
    int cntE = j1 - j0;
    if (cntE > CSR_CAP) cntE = CSR_CAP;
    {
        const uint4* src = reinterpret_cast<const uint4*>(csr + j0);
        int n4 = cntE >> 2;
        for (int k = tid; k < n4; k += 256)
            reinterpret_cast<uint4*>(lcsr)[k] = src[k];
    }
    for (int k = tid; k < 4096; k += 256) plane[k] = 0.f;

    int js = rowptr[r_own] - j0;
    int je = rowptr[r_own + 1] - j0;
    if (js > CSR_CAP) js = CSR_CAP;
    if (je > CSR_CAP) je = CSR_CAP;
    float av = a[r_own];
    float oma = 1.f - av;
    __syncthreads();

    float u_cur = W_in[(size_t)ltok[0] * N_RES + r_own];

    for (int t = 0; t < T_STEPS; ++t) {
        float u_nxt = 0.f;
        if (t + 1 < T_STEPS)
            u_nxt = W_in[(size_t)ltok[t + 1] * N_RES + r_own];

        float acc = 0.f;
        for (int j = js; j < je; j += 8) {
            uint4 e0 = *reinterpret_cast<const uint4*>(lcsr + j);
            uint4 e1 = *reinterpret_cast<const uint4*>(lcsr + j + 4);
            unsigned ee[8] = { e0.x, e0.y, e0.z, e0.w, e1.x, e1.y, e1.z, e1.w };
#pragma unroll
            for (int q = 0; q < 8; ++q) {
                float g = *reinterpret_cast<const float*>(
                    reinterpret_cast<const char*>(plane) + (ee[q] >> 16));
                acc += h2f((unsigned short)(ee[q] & 0xffffu)) * g;
            }
        }
        float hold = plane[r_own];
        float pre = u_cur + acc;
        pre = fminf(fmaxf(pre, -10.f), 10.f);
        float ex = __expf(2.f * pre);
        float th = 1.f - 2.f / (ex + 1.f);
        float hv = oma * hold + av * th;
        unsigned short hv16 = f2h(hv);
        Hb[((size_t)(team * T_STEPS + t) << 12) + r_own] = hv16;
        u_cur = u_nxt;

        if (t == T_STEPS - 1) break;

        unsigned e = (unsigned)(t + 1);
        size_t pofs = (((size_t)(e & 1u) * TEAMS + team) << 12);
        unsigned tagged = (e << 16) | (unsigned)hv16;

        // dual publish (both fire-and-forget)
        __hip_atomic_store(hxL + pofs + r_own, tagged,
                           __ATOMIC_RELAXED, __HIP_MEMORY_SCOPE_WORKGROUP);
        __hip_atomic_store(hxG + pofs + r_own, tagged,
                           __ATOMIC_RELAXED, __HIP_MEMORY_SCOPE_AGENT);

        // pull 16 rows (= 8 u64) for rows 16*tid .. 16*tid+15
        unsigned long long g[8];
        bool fb = (s_fb != 0);
#define TAGOK64(v) ((((unsigned)((v) >> 16) & 0xffffu) == e) && ((unsigned)((v) >> 48) == e))
        if (!fb) {
            uint4 q0, q1, q2, q3;
            const char* pL = reinterpret_cast<const char*>(hxL + pofs) + (size_t)tid * 64;
            int tries = 0;
            for (;;) {
                asm volatile("global_load_dwordx4 %0, %1, off sc0"
                             : "=v"(q0) : "v"(pL) : "memory");
                asm volatile("global_load_dwordx4 %0, %1, off offset:16 sc0"
                             : "=v"(q1) : "v"(pL) : "memory");
                asm volatile("global_load_dwordx4 %0, %1, off offset:32 sc0"
                             : "=v"(q2) : "v"(pL) : "memory");
                asm volatile("global_load_dwordx4 %0, %1, off offset:48 sc0"
                             : "=v"(q3) : "v"(pL) : "memory");
                asm volatile("s_waitcnt vmcnt(0)" ::: "memory");
                g[0] = (unsigned long long)q0.x | ((unsigned long long)q0.y << 32);
                g[1] = (unsigned long long)q0.z | ((unsigned long long)q0.w << 32);
                g[2] = (unsigned long long)q1.x | ((unsigned long long)q1.y << 32);
                g[3] = (unsigned long long)q1.z | ((unsigned long long)q1.w << 32);
                g[4] = (unsigned long long)q2.x | ((unsigned long long)q2.y << 32);
                g[5] = (unsigned long long)q2.z | ((unsigned long long)q2.w << 32);
                g[6] = (unsigned long long)q3.x | ((unsigned long long)q3.y << 32);
                g[7] = (unsigned long long)q3.z | ((unsigned long long)q3.w << 32);
                bool ok = true;
#pragma unroll
                for (int k = 0; k < 8; ++k) ok = ok && TAGOK64(g[k]);
                if (ok) break;
                if (++tries > 256) { fb = true; s_fb = 1; break; }
            }
        }
        if (fb) {
            const unsigned long long* xG64 =
                reinterpret_cast<const unsigned long long*>(hxG + pofs) + (size_t)tid * 8;
#pragma unroll
            for (int k = 0; k < 8; ++k)
                g[k] = __hip_atomic_load(xG64 + k, __ATOMIC_RELAXED,
                                         __HIP_MEMORY_SCOPE_AGENT);
            for (;;) {
                unsigned m = 0;
#pragma unroll
                for (int k = 0; k < 8; ++k)
                    m |= TAGOK64(g[k]) ? 0u : (1u << k);
                if (!m) break;
#pragma unroll
                for (int k = 0; k < 8; ++k)
                    if (m & (1u << k))
                        g[k] = __hip_atomic_load(xG64 + k, __ATOMIC_RELAXED,
                                                 __HIP_MEMORY_SCOPE_AGENT);
            }
        }
#undef TAGOK64

        __syncthreads();            // all gathers from old plane done
#pragma unroll
        for (int k = 0; k < 8; ++k) {
            float2 v;
            v.x = h2f((unsigned short)(g[k] & 0xffffu));
            v.y = h2f((unsigned short)((g[k] >> 32) & 0xffffu));
            *reinterpret_cast<float2*>(&plane[16 * tid + 2 * k]) = v;
        }
        __syncthreads();            // new plane ready
    }
}

// ---------------- staged-GEMM common: 128x32 f16 tile via global_load_lds ----------------

static __device__ __forceinline__ void stage128x32(const _Float16* __restrict__ g,
                                                   int ld, int row0, int k0,
                                                   _Float16* lds, int wave, int lane) {
#pragma unroll
    for (int q = 0; q < 2; ++q) {
        int i = wave * 128 + q * 64 + lane;
        const _Float16* src = g + (size_t)(row0 + (i >> 2)) * ld + k0 + (i & 3) * 8;
        int loff = __builtin_amdgcn_readfirstlane((wave * 128 + q * 64) * 16);
        __builtin_amdgcn_global_load_lds(
            (const __attribute__((address_space(1))) void*)src,
            (__attribute__((address_space(3))) void*)((char*)lds + loff),
            16, 0, 0);
    }
}

// ---------------- GEMM1: Rbh(2048x512,f16) = Hb(2048x4096,f16) @ Bwh^T ----------------

__global__ __launch_bounds__(256) void k_gemm1(const _Float16* __restrict__ Hb,
                                               const _Float16* __restrict__ Bwh,
                                               unsigned short* __restrict__ Rbh) {
    __shared__ _Float16 As[2][128 * 32];
    __shared__ _Float16 Bs[2][128 * 32];
    int tid = threadIdx.x, lane = tid & 63, wave = tid >> 6;
    int wm = wave >> 1, wn = wave & 1;
    int col0 = blockIdx.x * 128;
    int row0 = blockIdx.y * 128;
    int rA = lane & 15, kA = (lane >> 4) * 8;
    v4f acc[4][4];
#pragma unroll
    for (int s = 0; s < 4; ++s)
#pragma unroll
        for (int f = 0; f < 4; ++f) acc[s][f] = (v4f){0.f, 0.f, 0.f, 0.f};

    stage128x32(Hb,  N_RES, row0, 0, As[0], wave, lane);
    stage128x32(Bwh, N_RES, col0, 0, Bs[0], wave, lane);
    const int NIT = N_RES / 32;   // 128
    for (int it = 0; it < NIT; ++it) {
        int cur = it & 1;
        __syncthreads();
        asm volatile("s_waitcnt vmcnt(0)" ::: "memory");
        __syncthreads();
        if (it + 1 < NIT) {
            stage128x32(Hb,  N_RES, row0, (it + 1) * 32, As[cur ^ 1], wave, lane);
            stage128x32(Bwh, N_RES, col0, (it + 1) * 32, Bs[cur ^ 1], wave, lane);
        }
        v8h af[4], bf[4];
#pragma unroll
        for (int s = 0; s < 4; ++s)
            af[s] = *reinterpret_cast<const v8h*>(&As[cur][(wm * 64 + s * 16 + rA) * 32 + kA]);
#pragma unroll
        for (int f = 0; f < 4; ++f)
            bf[f] = *reinterpret_cast<const v8h*>(&Bs[cur][(wn * 64 + f * 16 + rA) * 32 + kA]);
#pragma unroll
        for (int s = 0; s < 4; ++s)
#pragma unroll
            for (int f = 0; f < 4; ++f)
                acc[s][f] = __builtin_amdgcn_mfma_f32_16x16x32_f16(af[s], bf[f], acc[s][f], 0, 0, 0);
    }
#pragma unroll
    for (int f = 0; f < 4; ++f) {
        int col = col0 + wn * 64 + f * 16 + (lane & 15);
#pragma unroll
        for (int s = 0; s < 4; ++s)
#pragma unroll
            for (int r = 0; r < 4; ++r) {
                int row = row0 + wm * 64 + s * 16 + (lane >> 4) * 4 + r;
                Rbh[(size_t)row * R_OUT + col] = f2h(acc[s][f][r]);
            }
    }
}

// ---------------- GEMM2: out(2048x32000,f32) = Rbh(f16) @ Awh^T + Ab ----------------

__global__ __launch_bounds__(256) void k_gemm2(const _Float16* __restrict__ Rbh,
                                               const _Float16* __restrict__ Awh,
                                               const float* __restrict__ Ab,
                                               float* __restrict__ out) {
    __shared__ _Float16 As[2][128 * 32];
    __shared__ _Float16 Bs[2][128 * 32];
    int tid = threadIdx.x, lane = tid & 63, wave = tid >> 6;
    int wm = wave >> 1, wn = wave & 1;
    int col0 = blockIdx.x * 128;
    int row0 = blockIdx.y * 128;
    int rA = lane & 15, kA = (lane >> 4) * 8;
    v4f acc[4][4];
#pragma unroll
    for (int s = 0; s < 4; ++s)
#pragma unroll
        for (int f = 0; f < 4; ++f) acc[s][f] = (v4f){0.f, 0.f, 0.f, 0.f};

    stage128x32(Rbh, R_OUT, row0, 0, As[0], wave, lane);
    stage128x32(Awh, R_OUT, col0, 0, Bs[0], wave, lane);
    const int NIT = R_OUT / 32;   // 16
    for (int it = 0; it < NIT; ++it) {
        int cur = it & 1;
        __syncthreads();
        asm volatile("s_waitcnt vmcnt(0)" ::: "memory");
        __syncthreads();
        if (it + 1 < NIT) {
            stage128x32(Rbh, R_OUT, row0, (it + 1) * 32, As[cur ^ 1], wave, lane);
            stage128x32(Awh, R_OUT, col0, (it + 1) * 32, Bs[cur ^ 1], wave, lane);
        }
        v8h af[4], bf[4];
#pragma unroll
        for (int s = 0; s < 4; ++s)
            af[s] = *reinterpret_cast<const v8h*>(&As[cur][(wm * 64 + s * 16 + rA) * 32 + kA]);
#pragma unroll
        for (int f = 0; f < 4; ++f)
            bf[f] = *reinterpret_cast<const v8h*>(&Bs[cur][(wn * 64 + f * 16 + rA) * 32 + kA]);
#pragma unroll
        for (int s = 0; s < 4; ++s)
#pragma unroll
            for (int f = 0; f < 4; ++f)
                acc[s][f] = __builtin_amdgcn_mfma_f32_16x16x32_f16(af[s], bf[f], acc[s][f], 0, 0, 0);
    }
#pragma unroll
    for (int f = 0; f < 4; ++f) {
        float bias = Ab[col0 + wn * 64 + f * 16 + (lane & 15)];
#pragma unroll
        for (int s = 0; s < 4; ++s)
#pragma unroll
            for (int r = 0; r < 4; ++r) acc[s][f][r] += bias;
    }
    float* Ct = (float*)As;
#pragma unroll
    for (int s = 0; s < 4; ++s) {
        __syncthreads();
#pragma unroll
        for (int f = 0; f < 4; ++f) {
            int lc = wn * 64 + f * 16 + (lane & 15);
            int lr = wm * 16 + (lane >> 4) * 4;
#pragma unroll
            for (int r = 0; r < 4; ++r)
                Ct[(lr + r) * 128 + lc] = acc[s][f][r];
        }
        __syncthreads();
        int lr2 = tid >> 3;
        int lc2 = (tid & 7) * 16;
        int grow = row0 + (lr2 & 15) + (lr2 >> 4) * 64 + s * 16;
        float* dst = out + (size_t)grow * VOCAB + col0 + lc2;
        const float* srcl = &Ct[lr2 * 128 + lc2];
#pragma unroll
        for (int v = 0; v < 4; ++v)
            *reinterpret_cast<float4*>(dst + v * 4) =
                *reinterpret_cast<const float4*>(srcl + v * 4);
    }
}

// ---------------- host launch ----------------

extern "C" void kernel_launch(void* const* d_in, const int* in_sizes, int n_in,
                              void* d_out, int out_size, void* d_ws, size_t ws_size,
                              hipStream_t stream) {
    const int*   x        = (const int*)d_in[0];
    const float* W_in     = (const float*)d_in[1];
    const int*   rec_rows = (const int*)d_in[2];
    const int*   rec_cols = (const int*)d_in[3];
    const float* rec_vals = (const float*)d_in[4];
    const float* a        = (const float*)d_in[5];
    const float* B_w      = (const float*)d_in[6];
    const float* A_w      = (const float*)d_in[7];
    const float* A_b      = (const float*)d_in[8];
    float* out = (float*)d_out;

    char* w = (char*)d_ws;
    size_t off = 0;
    auto alloc = [&](size_t bytes) { void* p = w + off; off = (off + bytes + 255) & ~(size_t)255; return p; };

    unsigned short* Hb     = (unsigned short*)alloc((size_t)2048 * N_RES * 2);   // 16.8 MB
    unsigned short* Rbh    = (unsigned short*)alloc((size_t)2048 * R_OUT * 2);   // 2.1 MB
    unsigned short* Bwh    = (unsigned short*)alloc((size_t)R_OUT * N_RES * 2);  // 4.2 MB
    unsigned short* Awh    = (unsigned short*)alloc((size_t)VOCAB * R_OUT * 2);  // 32.8 MB
    unsigned*       csr    = (unsigned*)alloc((size_t)NNZ_CAP * 4);              // 655 KB
    int*            rowptr = (int*)alloc(4097 * 4);
    int*            cnt    = (int*)alloc(4096 * 4);
    int*            cursor = (int*)alloc(4096 * 4);
    unsigned*       hxL    = (unsigned*)alloc((size_t)HX_WORDS * 4);             // 256 KB
    unsigned*       hxG    = (unsigned*)alloc((size_t)HX_WORDS * 4);             // 256 KB

    k_init<<<(INIT_WORDS + 255) / 256, 256, 0, stream>>>(csr, cnt, hxL, hxG);

    k_hist<<<(NNZ + 255) / 256, 256, 0, stream>>>(rec_rows, cnt);
    k_scan<<<1, 1024, 0, stream>>>(cnt, rowptr, cursor);
    k_fill<<<(NNZ + 255) / 256, 256, 0, stream>>>(rec_rows, rec_cols, rec_vals, cursor, csr);

    k_cvt2<<<(NB8 + NA8 + 255) / 256, 256, 0, stream>>>(B_w, Bwh, A_w, Awh);

    k_steps<<<NWG, 256, 0, stream>>>(rowptr, csr, W_in, x, a, Hb, hxL, hxG);

    k_gemm1<<<dim3(R_OUT / 128, 2048 / 128), 256, 0, stream>>>(
        (const _Float16*)Hb, (const _Float16*)Bwh, Rbh);
    k_gemm2<<<dim3(VOCAB / 128, 2048 / 128), 256, 0, stream>>>(
        (const _Float16*)Rbh, (const _Float16*)Awh, A_b, out);
}